// Round 1
// baseline (418.325 us; speedup 1.0000x reference)
//
#include <hip/hip_runtime.h>
#include <hip/hip_bf16.h>

typedef unsigned short ushort_t;

#define B_ 64
#define S_ 512
#define E_ 256
#define H_ 128
#define M_ (B_ * S_)   // 32768 rows
#define CAP_ 128       // max neighbor-list slots per row (nnz ~ Binom(512,0.05), mean 25.6)

// ---------------------------------------------------------------------------
// K1: build per-row neighbor index lists from binary adj + invdeg = 1/(nnz+1)
// one wave (64 lanes) per row, ballot compaction over 8 chunks of 64
// ---------------------------------------------------------------------------
__global__ void k_adjidx(const float* __restrict__ adj,
                         ushort_t* __restrict__ idxl,
                         int* __restrict__ nnz,
                         float* __restrict__ invdeg) {
    int row  = blockIdx.x * 4 + (threadIdx.x >> 6);
    int lane = threadIdx.x & 63;
    const float* arow = adj + (size_t)row * S_;
    int total = 0;
    #pragma unroll
    for (int c = 0; c < 8; ++c) {
        float v = arow[c * 64 + lane];
        unsigned long long m = __ballot(v != 0.0f);
        if (v != 0.0f) {
            int pos = total + __popcll(m & ((1ull << lane) - 1ull));
            if (pos < CAP_) idxl[(size_t)row * CAP_ + pos] = (ushort_t)(c * 64 + lane);
        }
        total += __popcll(m);
    }
    if (lane == 0) {
        nnz[row] = total < CAP_ ? total : CAP_;
        invdeg[row] = 1.0f / (float)(total + 1);
    }
}

// ---------------------------------------------------------------------------
// K2: embedding gather, float4, 4 rows per 256-thread block
// ---------------------------------------------------------------------------
__global__ void k_embed(const int* __restrict__ sent,
                        const float* __restrict__ emb,
                        float* __restrict__ h) {
    int row  = blockIdx.x * 4 + (threadIdx.x >> 6);
    int lane = threadIdx.x & 63;                 // 64 float4 per 256-float row
    int tok  = sent[row];
    const float4* src = (const float4*)(emb + (size_t)tok * E_);
    float4*       dst = (float4*)(h + (size_t)row * E_);
    dst[lane] = src[lane];
}

// ---------------------------------------------------------------------------
// K3: sparse aggregate X[row] = h[row] + sum_{t in nbr(row)} h[b, t]
// 64-thread blocks; float4 lanes; ROWS = 256/EDIM rows per block
// ---------------------------------------------------------------------------
template <int EDIM>
__global__ void k_agg(const float* __restrict__ h,
                      const ushort_t* __restrict__ idxl,
                      const int* __restrict__ nnz,
                      float* __restrict__ x) {
    constexpr int LPR  = EDIM / 4;   // lanes per row (float4): 64 or 32
    constexpr int ROWS = 64 / LPR;   // 1 or 2
    int row  = blockIdx.x * ROWS + threadIdx.x / LPR;
    int lane = threadIdx.x % LPR;
    int b    = row >> 9;
    const float4* h4 = (const float4*)h;
    int n = nnz[row];
    const ushort_t* il = idxl + (size_t)row * CAP_;
    float4 acc = h4[(size_t)row * LPR + lane];
    size_t base = (size_t)b * S_ * LPR;
    for (int i = 0; i < n; ++i) {
        int t = il[i];
        float4 v = h4[base + (size_t)t * LPR + lane];
        acc.x += v.x; acc.y += v.y; acc.z += v.z; acc.w += v.w;
    }
    ((float4*)x)[(size_t)row * LPR + lane] = acc;
}

// ---------------------------------------------------------------------------
// K4: out[row,j] = relu((X[row,:] . W[j,:] + 2*bias[j]) * invdeg[row])
// M x KDIM @ (128 x KDIM)^T ; BM=64 BN=128 BK=16, 256 threads, 8x4 micro-tile
// ---------------------------------------------------------------------------
template <int KDIM>
__global__ __launch_bounds__(256) void k_gemm(const float* __restrict__ X,
                                              const float* __restrict__ W,
                                              const float* __restrict__ bias,
                                              const float* __restrict__ invdeg,
                                              float* __restrict__ out) {
    const int BM = 64, BK = 16;
    __shared__ float Xs[BK][68];    // [k][m], stride 68: 16B-aligned rows, low conflicts
    __shared__ float Ws[BK][132];   // [k][n]
    int tid = threadIdx.x;
    int rowBlock = blockIdx.x * BM;
    int r0 = (tid >> 5) * 8;        // 0..56
    int c0 = (tid & 31) * 4;        // 0..124
    float acc[8][4] = {};

    for (int kk = 0; kk < KDIM; kk += BK) {
        {   // X tile: 64 x 16, 4 elems/thread
            int k = tid & 15;
            int m = tid >> 4;
            #pragma unroll
            for (int i = 0; i < 4; ++i)
                Xs[k][m + i * 16] = X[(size_t)(rowBlock + m + i * 16) * KDIM + kk + k];
        }
        {   // W tile: 128 x 16 (transposed into k-major), 8 elems/thread
            int j  = tid >> 1;
            int k0 = (tid & 1) * 8;
            const float* wp = W + (size_t)j * KDIM + kk + k0;
            #pragma unroll
            for (int i = 0; i < 8; ++i) Ws[k0 + i][j] = wp[i];
        }
        __syncthreads();
        #pragma unroll
        for (int k = 0; k < BK; ++k) {
            float xv[8], wv[4];
            #pragma unroll
            for (int i = 0; i < 8; ++i) xv[i] = Xs[k][r0 + i];
            #pragma unroll
            for (int j = 0; j < 4; ++j) wv[j] = Ws[k][c0 + j];
            #pragma unroll
            for (int i = 0; i < 8; ++i)
                #pragma unroll
                for (int j = 0; j < 4; ++j) acc[i][j] += xv[i] * wv[j];
        }
        __syncthreads();
    }

    float bv[4];
    #pragma unroll
    for (int j = 0; j < 4; ++j) bv[j] = 2.0f * bias[c0 + j];
    #pragma unroll
    for (int i = 0; i < 8; ++i) {
        int row = rowBlock + r0 + i;
        float inv = invdeg[row];
        float4 o;
        o.x = fmaxf((acc[i][0] + bv[0]) * inv, 0.0f);
        o.y = fmaxf((acc[i][1] + bv[1]) * inv, 0.0f);
        o.z = fmaxf((acc[i][2] + bv[2]) * inv, 0.0f);
        o.w = fmaxf((acc[i][3] + bv[3]) * inv, 0.0f);
        *(float4*)(out + (size_t)row * H_ + c0) = o;
    }
}

// ---------------------------------------------------------------------------
// K5: partial max-pool over 64 sequence positions per block
// ---------------------------------------------------------------------------
__global__ void k_pool(const float* __restrict__ h, float* __restrict__ pp) {
    int b = blockIdx.x, sb = blockIdx.y, j = threadIdx.x;  // 128 threads
    const float* p = h + ((size_t)b * S_ + sb * 64) * H_ + j;
    float m = -1e30f;
    #pragma unroll 8
    for (int s = 0; s < 64; ++s) m = fmaxf(m, p[(size_t)s * H_]);
    pp[((size_t)b * 8 + sb) * H_ + j] = m;
}

// ---------------------------------------------------------------------------
// K6: finish pool + logits[b,c] = pooled[b,:] . Wp[c,:] + bp[c]
// ---------------------------------------------------------------------------
__global__ void k_final(const float* __restrict__ pp,
                        const float* __restrict__ Wp,
                        const float* __restrict__ bp,
                        float* __restrict__ out) {
    int b = blockIdx.x, j = threadIdx.x;  // 128 threads
    float m = -1e30f;
    #pragma unroll
    for (int i = 0; i < 8; ++i) m = fmaxf(m, pp[((size_t)b * 8 + i) * H_ + j]);
    float t0 = m * Wp[j];
    float t1 = m * Wp[H_ + j];
    #pragma unroll
    for (int off = 32; off > 0; off >>= 1) {
        t0 += __shfl_down(t0, off);
        t1 += __shfl_down(t1, off);
    }
    __shared__ float red[2][2];
    int wave = j >> 6, lane = j & 63;
    if (lane == 0) { red[0][wave] = t0; red[1][wave] = t1; }
    __syncthreads();
    if (j == 0) out[b * 2 + 0] = red[0][0] + red[0][1] + bp[0];
    if (j == 1) out[b * 2 + 1] = red[1][0] + red[1][1] + bp[1];
}

// ---------------------------------------------------------------------------
extern "C" void kernel_launch(void* const* d_in, const int* in_sizes, int n_in,
                              void* d_out, int out_size, void* d_ws, size_t ws_size,
                              hipStream_t stream) {
    const int*   sent = (const int*)d_in[0];
    const float* adj  = (const float*)d_in[1];
    const float* emb  = (const float*)d_in[2];
    const float* W1   = (const float*)d_in[3];
    const float* b1   = (const float*)d_in[4];
    const float* W2   = (const float*)d_in[5];
    const float* b2   = (const float*)d_in[6];
    const float* W3   = (const float*)d_in[7];
    const float* b3   = (const float*)d_in[8];
    const float* Wp   = (const float*)d_in[9];
    const float* bp   = (const float*)d_in[10];
    float* out = (float*)d_out;

    char* ws = (char*)d_ws;
    float*    bufA   = (float*)ws;                                  // M*256 f32 = 32 MiB
    float*    bufB   = (float*)(ws + (size_t)M_ * 256 * 4);         // M*256 f32 = 32 MiB
    float*    invdeg = (float*)(ws + (size_t)M_ * 512 * 4);         // M f32
    int*      nnz    = (int*)(ws + (size_t)M_ * 512 * 4 + M_ * 4);
    ushort_t* idxl   = (ushort_t*)(ws + (size_t)M_ * 512 * 4 + M_ * 8);          // M*CAP u16
    float*    pp     = (float*)(ws + (size_t)M_ * 512 * 4 + M_ * 8 + (size_t)M_ * CAP_ * 2);

    k_adjidx<<<M_ / 4, 256, 0, stream>>>(adj, idxl, nnz, invdeg);
    k_embed <<<M_ / 4, 256, 0, stream>>>(sent, emb, bufA);

    k_agg<256><<<M_,     64, 0, stream>>>(bufA, idxl, nnz, bufB);
    k_gemm<256><<<M_ / 64, 256, 0, stream>>>(bufB, W1, b1, invdeg, bufA);

    k_agg<128><<<M_ / 2, 64, 0, stream>>>(bufA, idxl, nnz, bufB);
    k_gemm<128><<<M_ / 64, 256, 0, stream>>>(bufB, W2, b2, invdeg, bufA);

    k_agg<128><<<M_ / 2, 64, 0, stream>>>(bufA, idxl, nnz, bufB);
    k_gemm<128><<<M_ / 64, 256, 0, stream>>>(bufB, W3, b3, invdeg, bufA);

    k_pool <<<dim3(B_, 8), H_, 0, stream>>>(bufA, pp);
    k_final<<<B_, H_, 0, stream>>>(pp, Wp, bp, out);
}

// Round 2
// 314.269 us; speedup vs baseline: 1.3311x; 1.3311x over previous
//
#include <hip/hip_runtime.h>
#include <hip/hip_bf16.h>

typedef unsigned short ushort_t;

#define B_ 64
#define S_ 512
#define E_ 256
#define H_ 128
#define M_ (B_ * S_)   // 32768 rows
#define CAP_ 128       // max neighbor slots (nnz ~ Binom(512,0.05): mean 25.6, max ~55)

// ---------------------------------------------------------------------------
// K1: build per-row neighbor index lists from binary adj + invdeg = 1/(nnz+1)
// ---------------------------------------------------------------------------
__global__ void k_adjidx(const float* __restrict__ adj,
                         ushort_t* __restrict__ idxl,
                         int* __restrict__ nnz,
                         float* __restrict__ invdeg) {
    int row  = blockIdx.x * 4 + (threadIdx.x >> 6);
    int lane = threadIdx.x & 63;
    const float* arow = adj + (size_t)row * S_;
    int total = 0;
    #pragma unroll
    for (int c = 0; c < 8; ++c) {
        float v = arow[c * 64 + lane];
        unsigned long long m = __ballot(v != 0.0f);
        if (v != 0.0f) {
            int pos = total + __popcll(m & ((1ull << lane) - 1ull));
            if (pos < CAP_) idxl[(size_t)row * CAP_ + pos] = (ushort_t)(c * 64 + lane);
        }
        total += __popcll(m);
    }
    if (lane == 0) {
        nnz[row] = total < CAP_ ? total : CAP_;
        invdeg[row] = 1.0f / (float)(total + 1);
    }
}

// ---------------------------------------------------------------------------
// K2: GEMM  Y[row,:] = X[row,:] @ W^T   (pure matmul; epilogue lives in agg)
// GATHER: X[row,:] = emb[sent[row],:]  (fused embedding, layer 1)
// BM=64 BN=128 BK=16, 256 threads, 8x4 micro-tile, float4 LDS reads
// ---------------------------------------------------------------------------
template <int KDIM, bool GATHER>
__global__ __launch_bounds__(256) void k_gemm(const float* __restrict__ X,
                                              const int* __restrict__ sent,
                                              const float* __restrict__ emb,
                                              const float* __restrict__ W,
                                              float* __restrict__ out) {
    const int BK = 16;
    __shared__ float Xs[BK][68];    // [k][m], stride 68 (272B: 16B-aligned rows)
    __shared__ float Ws[BK][132];   // [k][n], stride 132 (528B)
    int tid = threadIdx.x;
    int rowBlock = blockIdx.x * 64;
    int r0 = (tid >> 5) * 8;        // 0..56
    int c0 = (tid & 31) * 4;        // 0..124
    float acc[8][4] = {};

    // staging source pointers (hoisted; sent[] read once)
    int mIdx = tid >> 2;                       // 0..63
    int k4   = (tid & 3) * 4;
    const float* xsrc;
    if (GATHER) xsrc = emb + (size_t)sent[rowBlock + mIdx] * KDIM + k4;
    else        xsrc = X   + (size_t)(rowBlock + mIdx) * KDIM + k4;
    int wj = tid >> 1;                         // 0..127
    int k8 = (tid & 1) * 8;
    const float* wsrc = W + (size_t)wj * KDIM + k8;

    for (int kk = 0; kk < KDIM; kk += BK) {
        float4 xf = *(const float4*)(xsrc + kk);
        float4 w0 = *(const float4*)(wsrc + kk);
        float4 w1 = *(const float4*)(wsrc + kk + 4);
        Xs[k4 + 0][mIdx] = xf.x; Xs[k4 + 1][mIdx] = xf.y;
        Xs[k4 + 2][mIdx] = xf.z; Xs[k4 + 3][mIdx] = xf.w;
        Ws[k8 + 0][wj] = w0.x; Ws[k8 + 1][wj] = w0.y;
        Ws[k8 + 2][wj] = w0.z; Ws[k8 + 3][wj] = w0.w;
        Ws[k8 + 4][wj] = w1.x; Ws[k8 + 5][wj] = w1.y;
        Ws[k8 + 6][wj] = w1.z; Ws[k8 + 7][wj] = w1.w;
        __syncthreads();
        #pragma unroll
        for (int k = 0; k < BK; ++k) {
            float4 a0 = *(const float4*)&Xs[k][r0];
            float4 a1 = *(const float4*)&Xs[k][r0 + 4];
            float4 wv = *(const float4*)&Ws[k][c0];
            float xv[8] = {a0.x, a0.y, a0.z, a0.w, a1.x, a1.y, a1.z, a1.w};
            #pragma unroll
            for (int i = 0; i < 8; ++i) {
                acc[i][0] += xv[i] * wv.x;
                acc[i][1] += xv[i] * wv.y;
                acc[i][2] += xv[i] * wv.z;
                acc[i][3] += xv[i] * wv.w;
            }
        }
        __syncthreads();
    }

    #pragma unroll
    for (int i = 0; i < 8; ++i) {
        int row = rowBlock + r0 + i;
        float4 o = {acc[i][0], acc[i][1], acc[i][2], acc[i][3]};
        *(float4*)(out + (size_t)row * H_ + c0) = o;
    }
}

// ---------------------------------------------------------------------------
// K3: aggregate + epilogue:
//   h[row] = relu( (Y[row] + sum_{t in nbr(row)} Y[b,t] + 2b) * invdeg[row] )
// 256 threads = 8 rows x 32 float4-lanes. XCD-swizzled grid: all blocks of a
// batch share blockIdx%8 so the 256KB batch slab stays in one XCD's L2.
// ---------------------------------------------------------------------------
__global__ __launch_bounds__(256) void k_aggf(const float* __restrict__ Y,
                                              const ushort_t* __restrict__ idxl,
                                              const int* __restrict__ nnz,
                                              const float* __restrict__ invdeg,
                                              const float* __restrict__ bias,
                                              float* __restrict__ out) {
    int x    = blockIdx.x;            // 0..4095
    int xcd  = x & 7;
    int slot = x >> 3;                // 0..511
    int b    = xcd + 8 * (slot >> 6); // batches 0..63, fixed xcd per batch
    int g    = slot & 63;             // row-group within batch
    int row  = b * S_ + g * 8 + (threadIdx.x >> 5);
    int c    = threadIdx.x & 31;      // float4 column

    const float4* Y4 = (const float4*)Y;
    int n = nnz[row];
    const ushort_t* il = idxl + (size_t)row * CAP_;
    float4 acc = Y4[(size_t)row * 32 + c];
    float4 acc2 = {0.f, 0.f, 0.f, 0.f};
    size_t base = (size_t)b * S_ * 32;

    int i = 0;
    for (; i + 4 <= n; i += 4) {
        int t0 = il[i], t1 = il[i + 1], t2 = il[i + 2], t3 = il[i + 3];
        float4 v0 = Y4[base + (size_t)t0 * 32 + c];
        float4 v1 = Y4[base + (size_t)t1 * 32 + c];
        float4 v2 = Y4[base + (size_t)t2 * 32 + c];
        float4 v3 = Y4[base + (size_t)t3 * 32 + c];
        acc.x += v0.x + v1.x; acc.y += v0.y + v1.y;
        acc.z += v0.z + v1.z; acc.w += v0.w + v1.w;
        acc2.x += v2.x + v3.x; acc2.y += v2.y + v3.y;
        acc2.z += v2.z + v3.z; acc2.w += v2.w + v3.w;
    }
    for (; i < n; ++i) {
        int t = il[i];
        float4 v = Y4[base + (size_t)t * 32 + c];
        acc.x += v.x; acc.y += v.y; acc.z += v.z; acc.w += v.w;
    }
    acc.x += acc2.x; acc.y += acc2.y; acc.z += acc2.z; acc.w += acc2.w;

    float inv = invdeg[row];
    float4 bv = ((const float4*)bias)[c];
    float4 o;
    o.x = fmaxf((acc.x + 2.0f * bv.x) * inv, 0.0f);
    o.y = fmaxf((acc.y + 2.0f * bv.y) * inv, 0.0f);
    o.z = fmaxf((acc.z + 2.0f * bv.z) * inv, 0.0f);
    o.w = fmaxf((acc.w + 2.0f * bv.w) * inv, 0.0f);
    ((float4*)out)[(size_t)row * 32 + c] = o;
}

// ---------------------------------------------------------------------------
// K4: partial max-pool over 64 sequence positions per block
// ---------------------------------------------------------------------------
__global__ void k_pool(const float* __restrict__ h, float* __restrict__ pp) {
    int b = blockIdx.x, sb = blockIdx.y, j = threadIdx.x;  // 128 threads
    const float* p = h + ((size_t)b * S_ + sb * 64) * H_ + j;
    float m = -1e30f;
    #pragma unroll 8
    for (int s = 0; s < 64; ++s) m = fmaxf(m, p[(size_t)s * H_]);
    pp[((size_t)b * 8 + sb) * H_ + j] = m;
}

// ---------------------------------------------------------------------------
// K5: finish pool + logits[b,c] = pooled[b,:] . Wp[c,:] + bp[c]
// ---------------------------------------------------------------------------
__global__ void k_final(const float* __restrict__ pp,
                        const float* __restrict__ Wp,
                        const float* __restrict__ bp,
                        float* __restrict__ out) {
    int b = blockIdx.x, j = threadIdx.x;  // 128 threads
    float m = -1e30f;
    #pragma unroll
    for (int i = 0; i < 8; ++i) m = fmaxf(m, pp[((size_t)b * 8 + i) * H_ + j]);
    float t0 = m * Wp[j];
    float t1 = m * Wp[H_ + j];
    #pragma unroll
    for (int off = 32; off > 0; off >>= 1) {
        t0 += __shfl_down(t0, off);
        t1 += __shfl_down(t1, off);
    }
    __shared__ float red[2][2];
    int wave = j >> 6, lane = j & 63;
    if (lane == 0) { red[0][wave] = t0; red[1][wave] = t1; }
    __syncthreads();
    if (j == 0) out[b * 2 + 0] = red[0][0] + red[0][1] + bp[0];
    if (j == 1) out[b * 2 + 1] = red[1][0] + red[1][1] + bp[1];
}

// ---------------------------------------------------------------------------
extern "C" void kernel_launch(void* const* d_in, const int* in_sizes, int n_in,
                              void* d_out, int out_size, void* d_ws, size_t ws_size,
                              hipStream_t stream) {
    const int*   sent = (const int*)d_in[0];
    const float* adj  = (const float*)d_in[1];
    const float* emb  = (const float*)d_in[2];
    const float* W1   = (const float*)d_in[3];
    const float* b1   = (const float*)d_in[4];
    const float* W2   = (const float*)d_in[5];
    const float* b2   = (const float*)d_in[6];
    const float* W3   = (const float*)d_in[7];
    const float* b3   = (const float*)d_in[8];
    const float* Wp   = (const float*)d_in[9];
    const float* bp   = (const float*)d_in[10];
    float* out = (float*)d_out;

    char* ws = (char*)d_ws;
    float*    bufA   = (float*)ws;                                  // M*128 f32 = 16 MiB used
    float*    bufB   = (float*)(ws + (size_t)M_ * 256 * 4);         // M*128 f32
    float*    invdeg = (float*)(ws + (size_t)M_ * 512 * 4);         // M f32
    int*      nnz    = (int*)(ws + (size_t)M_ * 512 * 4 + M_ * 4);
    ushort_t* idxl   = (ushort_t*)(ws + (size_t)M_ * 512 * 4 + M_ * 8);          // M*CAP u16
    float*    pp     = (float*)(ws + (size_t)M_ * 512 * 4 + M_ * 8 + (size_t)M_ * CAP_ * 2);

    k_adjidx<<<M_ / 4, 256, 0, stream>>>(adj, idxl, nnz, invdeg);

    // layer 1: Y1 = emb[sent] @ W1^T  (fused embedding), then agg+epilogue
    k_gemm<E_, true><<<M_ / 64, 256, 0, stream>>>(nullptr, sent, emb, W1, bufA);
    k_aggf<<<M_ / 8, 256, 0, stream>>>(bufA, idxl, nnz, invdeg, b1, bufB);

    // layer 2
    k_gemm<H_, false><<<M_ / 64, 256, 0, stream>>>(bufB, nullptr, nullptr, W2, bufA);
    k_aggf<<<M_ / 8, 256, 0, stream>>>(bufA, idxl, nnz, invdeg, b2, bufB);

    // layer 3
    k_gemm<H_, false><<<M_ / 64, 256, 0, stream>>>(bufB, nullptr, nullptr, W3, bufA);
    k_aggf<<<M_ / 8, 256, 0, stream>>>(bufA, idxl, nnz, invdeg, b3, bufB);

    k_pool <<<dim3(B_, 8), H_, 0, stream>>>(bufB, pp);
    k_final<<<B_, H_, 0, stream>>>(pp, Wp, bp, out);
}